// Round 17
// baseline (102.565 us; speedup 1.0000x reference)
//
#include <hip/hip_runtime.h>
#include <hip/hip_bf16.h>
#include <math.h>

#define C_CLASSES 100000
#define EMBED     384
#define BATCH     512
#define S_SCALE   64.0f
#define COS_M_    0.8775825618903728f
#define SIN_M_    0.479425538604203f
#define TH_       (-0.8775825618903728f)
#define MM_       0.2397127693021015f
#define EPS_      1e-7f
#define LOG2E_    1.4426950408889634f
#define LN2_      0.6931471805599453f
#define BIGZ_     92.33261191693459f      /* 64 * log2(e) */
#define SK1_      92.33248f               /* fp32(S * log2(e)) */

#define CT    32
#define NCHK  3125                         // 100000 / 32 exact — NO tail
#define NBLK  (NCHK * 2)                   // x2 M-halves

typedef __attribute__((ext_vector_type(8))) short bf16x8;
typedef __attribute__((ext_vector_type(4))) float f32x4;

__device__ inline ushort f2bf(float f) {
    unsigned u = __float_as_uint(f);
    unsigned r = (u + 0x7fffu + ((u >> 16) & 1u)) >> 16;   // RNE
    return (ushort)r;
}

// ---------------------------------------------------------------------------
// Kernel 0: convert E to bf16, packed in MFMA A-fragment order:
//   eP[((tile*12 + ks)*64 + lane)*8 + j] = bf16(E[tile*16 + (lane&15)]
//                                               [ks*32 + (lane>>4)*8 + j])
// ---------------------------------------------------------------------------
__global__ __launch_bounds__(256)
void cvt_pack_e(const float* __restrict__ emb, ushort* __restrict__ eP)
{
    int t = blockIdx.x * 256 + threadIdx.x;      // 0 .. 24575
    int lane = t & 63;
    int grp  = t >> 6;                           // tile*12 + ks
    int tile = grp / 12, ks = grp % 12;
    int lr = lane & 15, lg = lane >> 4;
    int row = tile * 16 + lr;
    int col = ks * 32 + lg * 8;
    const float4* src = (const float4*)(emb + (size_t)row * EMBED + col);
    float4 v0 = src[0], v1 = src[1];
    ushort4 o0, o1;
    o0.x = f2bf(v0.x); o0.y = f2bf(v0.y); o0.z = f2bf(v0.z); o0.w = f2bf(v0.w);
    o1.x = f2bf(v1.x); o1.y = f2bf(v1.y); o1.z = f2bf(v1.z); o1.w = f2bf(v1.w);
    ((ushort4*)eP)[t * 2]     = o0;
    ((ushort4*)eP)[t * 2 + 1] = o1;
}

// ---------------------------------------------------------------------------
// Kernel 1: occupancy-first fused kernel.
// grid = 6250 (3125 chunks x 2 M-halves), 256 thr (4 waves), CT=32 classes.
// Wave w: rows mh*256 + w*64 .. +63 (4 Mtiles) x 32 classes (2 Ntiles),
// acc = 32 AGPR. launch_bounds(256,5) -> ~102-reg budget -> 5 blocks/CU
// (20 waves): five staggered blocks hide the stage latency structurally.
//  phase 1: W global->reg (two 16-row half-passes, 16 lanes/row, wv[6]),
//           fence between halves; sumsq butterfly; bank-swizzled pack.
//  phase 2: MFMA 4mt x 2nt x 12ks; A from L2-resident eP.
//  phase 3: fixed-max LSE + rare margin fixup. No tail anywhere (32|100000).
// ---------------------------------------------------------------------------
__global__ __launch_bounds__(256, 5)
void arc_fused32(const ushort* __restrict__ eP, const int* __restrict__ labels,
                 const float* __restrict__ weight,
                 float* __restrict__ psum, float* __restrict__ zlabel)
{
    __shared__ ushort Bl[(CT / 16) * 12 * 512];    // 12288 ushorts = 24576 B
    __shared__ int    labL[256];

    const int tid = threadIdx.x;

    // bijective XCD swizzle (m204): both M-halves of a chunk -> same XCD L2.
    const int orig = blockIdx.x;
    const int xcd  = orig & 7;
    const int qq   = NBLK >> 3, rr = NBLK & 7;     // 781, 2
    const int bid  = (xcd < rr ? xcd * (qq + 1)
                               : rr * (qq + 1) + (xcd - rr) * qq) + (orig >> 3);
    const int ck   = bid >> 1;                     // chunk 0..3124
    const int mh   = bid & 1;                      // M-half 0/1
    const int c0   = ck * CT;

    labL[tid] = labels[mh * 256 + tid];

    // ---- phase 1: two half-passes of 16 rows each (16 lanes/row) ----
    {
        const int p = tid & 15;
        #pragma unroll
        for (int h = 0; h < 2; ++h) {
            const int c = h * 16 + (tid >> 4);     // class 0..31
            const float4* src =
                (const float4*)(weight + (size_t)(c0 + c) * EMBED) + p;

            float4 wv[6];
            float ss = 0.f;
            #pragma unroll
            for (int i = 0; i < 6; ++i) {
                wv[i] = src[16 * i];
                ss += wv[i].x * wv[i].x + wv[i].y * wv[i].y
                    + wv[i].z * wv[i].z + wv[i].w * wv[i].w;
            }
            ss += __shfl_xor(ss, 1, 64);
            ss += __shfl_xor(ss, 2, 64);
            ss += __shfl_xor(ss, 4, 64);
            ss += __shfl_xor(ss, 8, 64);
            const float inv = (ss > 0.f) ? rsqrtf(ss) : 0.f;

            const int t2 = c >> 4, cl = c & 15;
            #pragma unroll
            for (int i = 0; i < 6; ++i) {
                int q   = p + 16 * i;        // quad index 0..95
                int ks  = q >> 3;
                int lgp = (q >> 1) & 3;
                int jo  = (q & 1) * 4;
                ushort4 o;
                o.x = f2bf(wv[i].x * inv); o.y = f2bf(wv[i].y * inv);
                o.z = f2bf(wv[i].z * inv); o.w = f2bf(wv[i].w * inv);
                int ei = (((t2 * 12 + ks) * 64) + cl + 16 * lgp) * 8 + jo;
                ei ^= (lgp & 3) << 4;                 // bank swizzle (write)
                *(ushort4*)&Bl[ei] = o;
            }
            __builtin_amdgcn_sched_barrier(0);        // anti-hoist fence
        }
    }
    __syncthreads();     // packed B + labL ready

    // ---- phase 2: MFMA, 4 waves x (4 Mtiles x 2 Ntiles), K=384 ----
    const int wid = tid >> 6, l = tid & 63;
    const int lr  = l & 15,  lg = l >> 4;
    const int bxo = (lg & 3) << 4;                    // bank swizzle (read)

    // A tiles: global row tile = mh*16 + wid*4 + mt
    const ushort* abase = eP + ((size_t)((mh * 16 + wid * 4) * 12) * 64 + l) * 8;

    f32x4 acc[4][2];
    #pragma unroll
    for (int mt = 0; mt < 4; ++mt) {
        acc[mt][0] = (f32x4){0.f, 0.f, 0.f, 0.f};
        acc[mt][1] = (f32x4){0.f, 0.f, 0.f, 0.f};
    }

    #pragma unroll
    for (int ks = 0; ks < 12; ++ks) {
        bf16x8 a[4], b[2];
        #pragma unroll
        for (int mt = 0; mt < 4; ++mt)
            a[mt] = *(const bf16x8*)(abase + (mt * 12 + ks) * 512);
        #pragma unroll
        for (int nt = 0; nt < 2; ++nt) {
            int ei = ((nt * 12 + ks) * 64 + l) * 8;
            b[nt] = *(const bf16x8*)&Bl[ei ^ bxo];
        }
        #pragma unroll
        for (int mt = 0; mt < 4; ++mt) {
            acc[mt][0] = __builtin_amdgcn_mfma_f32_16x16x32_bf16(
                a[mt], b[0], acc[mt][0], 0, 0, 0);
            acc[mt][1] = __builtin_amdgcn_mfma_f32_16x16x32_bf16(
                a[mt], b[1], acc[mt][1], 0, 0, 0);
        }
    }

    // ---- phase 3: fixed-max LSE + rare margin fixup (no tail) ----
    #pragma unroll
    for (int mt = 0; mt < 4; ++mt) {
        #pragma unroll
        for (int rg = 0; rg < 4; ++rg) {
            const int rl  = wid * 64 + mt * 16 + lg * 4 + rg;   // 0..255
            const int r   = mh * 256 + rl;                      // global row
            const int lab = labL[rl];
            float acc4 = 0.f;
            #pragma unroll
            for (int nt = 0; nt < 2; ++nt) {
                float cv = acc[mt][nt][rg];
                cv = fminf(fmaxf(cv, -1.f + EPS_), 1.f - EPS_);
                acc4 += exp2f(fmaf(cv, SK1_, -BIGZ_));
            }
            int off = lab - c0;
            if (((unsigned)off < 32u) && ((off & 15) == lr)) {
                float cv = (off >> 4) ? acc[mt][1][rg] : acc[mt][0][rg];
                cv = fminf(fmaxf(cv, -1.f + EPS_), 1.f - EPS_);
                float plain = exp2f(fmaf(cv, SK1_, -BIGZ_));
                float zm;
                if (cv > TH_) {
                    float sv = sqrtf(fmaxf(1.f - cv * cv, 0.f));
                    zm = S_SCALE * (cv * COS_M_ - sv * SIN_M_);
                } else {
                    zm = S_SCALE * (cv - MM_);
                }
                acc4 += exp2f(fmaf(zm, LOG2E_, -BIGZ_)) - plain;
                zlabel[r] = zm;
            }
            acc4 += __shfl_xor(acc4, 1, 64);
            acc4 += __shfl_xor(acc4, 2, 64);
            acc4 += __shfl_xor(acc4, 4, 64);
            acc4 += __shfl_xor(acc4, 8, 64);
            if (lr == 0) psum[(size_t)ck * BATCH + r] = acc4;
        }
    }
}

// ---------------------------------------------------------------------------
// Kernel 2: sum 3125 chunk-partials per row -> row loss
// ---------------------------------------------------------------------------
__global__ __launch_bounds__(256)
void arc_reduce(const float* __restrict__ psum, const float* __restrict__ zlabel,
                float* __restrict__ rowloss)
{
    const int r = blockIdx.x;
    const int tid = threadIdx.x;
    float s = 0.f;
    for (int k = tid; k < NCHK; k += 256)
        s += psum[(size_t)k * BATCH + r];
    #pragma unroll
    for (int d = 1; d < 64; d <<= 1) s += __shfl_xor(s, d, 64);
    __shared__ float ssh[4];
    if ((tid & 63) == 0) ssh[tid >> 6] = s;
    __syncthreads();
    if (tid == 0) {
        float t = ssh[0] + ssh[1] + ssh[2] + ssh[3];
        rowloss[r] = LN2_ * (BIGZ_ + log2f(t)) - zlabel[r];
    }
}

// ---------------------------------------------------------------------------
// Kernel 3: mean over rows
// ---------------------------------------------------------------------------
__global__ __launch_bounds__(512)
void arc_mean(const float* __restrict__ rowloss, float* __restrict__ out)
{
    const int tid = threadIdx.x;
    float v = rowloss[tid];
    #pragma unroll
    for (int d = 1; d < 64; d <<= 1) v += __shfl_xor(v, d, 64);
    __shared__ float sv[8];
    if ((tid & 63) == 0) sv[tid >> 6] = v;
    __syncthreads();
    if (tid == 0) {
        float t = 0.f;
        #pragma unroll
        for (int w = 0; w < 8; ++w) t += sv[w];
        out[0] = t / (float)BATCH;
    }
}

extern "C" void kernel_launch(void* const* d_in, const int* in_sizes, int n_in,
                              void* d_out, int out_size, void* d_ws, size_t ws_size,
                              hipStream_t stream)
{
    (void)in_sizes; (void)n_in; (void)out_size; (void)ws_size;
    const float* emb    = (const float*)d_in[0];
    const int*   labels = (const int*)d_in[1];
    const float* weight = (const float*)d_in[2];
    float* out = (float*)d_out;

    float*  psum    = (float*)d_ws;                    // [NCHK][BATCH]  6.4 MB
    float*  zlabel  = psum + (size_t)NCHK * BATCH;     // [BATCH]
    float*  rowloss = zlabel + BATCH;                  // [BATCH]
    ushort* eP      = (ushort*)(rowloss + BATCH);      // packed bf16 E frags

    cvt_pack_e<<<(BATCH * EMBED / 8) / 256, 256, 0, stream>>>(emb, eP);
    arc_fused32<<<NBLK, 256, 0, stream>>>(eP, labels, weight, psum, zlabel);
    arc_reduce<<<BATCH, 256, 0, stream>>>(psum, zlabel, rowloss);
    arc_mean<<<1, 512, 0, stream>>>(rowloss, out);
}